// Round 12
// baseline (107.974 us; speedup 1.0000x reference)
//
#include <hip/hip_runtime.h>
#include <hip/hip_bf16.h>

typedef __attribute__((ext_vector_type(8))) __bf16 bf16x8;
typedef __attribute__((ext_vector_type(4))) float f32x4;
typedef __attribute__((ext_vector_type(8))) unsigned short u16x8;

#define DEVI __device__ __forceinline__
#define MFMA(a,b,c) __builtin_amdgcn_mfma_f32_16x16x32_bf16((a),(b),(c),0,0,0)
#define EXP2F(x) __builtin_exp2f(x)
#define LOG2F(x) __builtin_log2f(x)

DEVI unsigned short f2bf(float f){ __bf16 h = (__bf16)f; return __builtin_bit_cast(unsigned short, h); }
DEVI float bf2f(unsigned short u){ unsigned int x = ((unsigned int)u) << 16; return __builtin_bit_cast(float, x); }
DEVI bf16x8 ld_bf8(const void* p){ u16x8 u = *(const u16x8*)p; return __builtin_bit_cast(bf16x8, u); }
DEVI f32x4 splat4(float x){ f32x4 v = {x,x,x,x}; return v; }
DEVI f32x4 vmax4(f32x4 a, f32x4 b){
  f32x4 r;
  #pragma unroll
  for (int i=0;i<4;++i) r[i]=fmaxf(a[i],b[i]);
  return r;
}
DEVI void gload_lds16(const void* g, void* l){
  void* g2 = const_cast<void*>(g);
  __builtin_amdgcn_global_load_lds((__attribute__((address_space(1))) void*)g2,
                                   (__attribute__((address_space(3))) void*)l, 16, 0, 0);
}
// cross-lane max over lane-bits 4 and 5 via permlane swap butterflies (pure VALU).
#if __has_builtin(__builtin_amdgcn_permlane16_swap) && __has_builtin(__builtin_amdgcn_permlane32_swap)
DEVI float wavemax_hi(float x){
  unsigned int xu = __builtin_bit_cast(unsigned int, x);
  auto r1 = __builtin_amdgcn_permlane16_swap(xu, xu, false, false);   // xor-16 pair
  float m = fmaxf(__builtin_bit_cast(float, (unsigned int)r1[0]),
                  __builtin_bit_cast(float, (unsigned int)r1[1]));
  unsigned int mu = __builtin_bit_cast(unsigned int, m);
  auto r2 = __builtin_amdgcn_permlane32_swap(mu, mu, false, false);   // xor-32 pair
  return fmaxf(__builtin_bit_cast(float, (unsigned int)r2[0]),
               __builtin_bit_cast(float, (unsigned int)r2[1]));
}
#else
DEVI float wavemax_hi(float x){
  x = fmaxf(x, __shfl_xor(x, 16, 64));
  x = fmaxf(x, __shfl_xor(x, 32, 64));
  return x;
}
#endif

// schedule table: 30 chunks per segment, heavy-first. qb | t0<<8 | ntiles<<16 | slot<<24 (64-row tile units)
__device__ const unsigned int SCHED[30] = {
  0x100C000Bu, 0x110C0C0Bu, 0x050C0005u, 0x1C0B0A0Fu, 0x1D0B150Fu,
  0x0E0B000Au, 0x0F0B0B0Au, 0x1B0A000Fu, 0x180A000Eu, 0x190A0A0Eu,
  0x1A0A140Eu, 0x170A120Du, 0x0C0A0009u, 0x0D0A0A09u, 0x040A0004u,
  0x1509000Du, 0x1609090Du, 0x1309080Cu, 0x1409110Cu, 0x0A090008u,
  0x0B090908u, 0x1208000Cu, 0x08080007u, 0x09080807u, 0x03080003u,
  0x06070006u, 0x07070706u, 0x02060002u, 0x01040001u, 0x00020000u
};
// canonical chunk-base per qb (prefix of nchunks {1x6, 2x6, 3x4})
__device__ const int CB[16] = {0,1,2,3,4,5,6,8,10,12,14,16,18,21,24,27};

// ---------------- prep: transpose weights to [mat][col][k] bf16; fold 1/(sqrt(c)*ln2) into Wq (base-2 softmax)
__global__ __launch_bounds__(256) void k_prep(const float* __restrict__ Wq, const float* __restrict__ Wk,
                                              const float* __restrict__ Wv, const float* __restrict__ Wo,
                                              unsigned short* __restrict__ wT){
  int i = blockIdx.x*256 + threadIdx.x;              // 0..65535
  int mat = i >> 14, col = (i >> 7) & 127, k = i & 127;
  const float* W = (mat==0)?Wq:(mat==1)?Wk:(mat==2)?Wv:Wo;
  float v = W[k*128 + col];
  if (mat == 0) v *= 0.12754245006257017f;           // 1/(sqrt(128)*ln2)
  wT[i] = f2bf(v);
}

// ---------------- QKV projection + in-kernel V transpose, kv-permuted V^T arrays.
// 512-thread blocks (8 waves, 16 rows/wave) -> 2 waves/SIMD.
__global__ __launch_bounds__(512) void k_qkv(const float* __restrict__ x, const unsigned short* __restrict__ wT,
                                             unsigned short* __restrict__ Qo, unsigned short* __restrict__ Ko,
                                             unsigned short* __restrict__ VT0, unsigned short* __restrict__ VT1,
                                             unsigned short* __restrict__ VT2){
  __shared__ unsigned short Tl[128*130];             // [token 0..127][d 0..127], row stride 130
  const int tid=threadIdx.x, lane=tid&63, wid=tid>>6, ll=lane&15, hi=lane>>4;
  const int row0g = blockIdx.x*128;
  const long row0 = (long)row0g + wid*16;            // 16 rows per wave, 8 waves
  bf16x8 a[4];
  {
    const float* xr = x + (row0 + ll)*128 + hi*8;
    #pragma unroll
    for (int ks=0;ks<4;++ks){
      f32x4 f0 = *(const f32x4*)(const void*)(xr + ks*32);
      f32x4 f1 = *(const f32x4*)(const void*)(xr + ks*32 + 4);
      u16x8 u;
      #pragma unroll
      for (int j=0;j<4;++j){ u[j]=f2bf(f0[j]); u[j+4]=f2bf(f1[j]); }
      a[ks] = __builtin_bit_cast(bf16x8, u);
    }
  }
  #pragma unroll
  for (int m3=0;m3<3;++m3){
    const unsigned short* wp = wT + m3*16384 + ll*128 + hi*8;
    #pragma unroll
    for (int nt=0;nt<8;++nt){
      f32x4 acc=splat4(0.f);
      #pragma unroll
      for (int ks=0;ks<4;++ks){
        bf16x8 b = ld_bf8(wp + nt*2048 + ks*32);
        acc = MFMA(a[ks], b, acc);
      }
      if (m3 < 2){
        unsigned short* outp = (m3==0)?Qo:Ko;
        #pragma unroll
        for (int r=0;r<4;++r)
          outp[(row0 + hi*4 + r)*128 + nt*16 + ll] = f2bf(acc[r]);
      } else {
        #pragma unroll
        for (int r=0;r<4;++r)
          Tl[(wid*16 + hi*4 + r)*130 + nt*16 + ll] = f2bf(acc[r]);
      }
    }
  }
  __syncthreads();
  // write-out V^T rows, kv-permuted within 32-rank blocks (rank pair 2*lane,2*lane+1 stays adjacent)
  int tk = 2*lane;
  int pp0 = (tk>>5)*32 + ((tk>>4)&1)*4 + ((tk&15)>>2)*8 + (tk&3);
  #pragma unroll 4
  for (int p=0;p<16;++p){
    int d = wid*16 + p;
    unsigned int w0 = (unsigned int)Tl[(2*lane)*130 + d] | ((unsigned int)Tl[(2*lane+1)*130 + d] << 16);
    *(unsigned int*)(VT0 + (long)d*32768 + row0g + pp0) = w0;
    if (lane < 32){
      unsigned int w1 = (unsigned int)Tl[(4*lane)*130 + d] | ((unsigned int)Tl[(4*lane+2)*130 + d] << 16);
      *(unsigned int*)(VT1 + (long)d*16384 + (row0g>>1) + pp0) = w1;
    }
    if (lane < 16){
      unsigned int w2 = (unsigned int)Tl[(8*lane)*130 + d] | ((unsigned int)Tl[(8*lane+4)*130 + d] << 16);
      *(unsigned int*)(VT2 + (long)d*8192 + (row0g>>2) + pp0) = w2;
    }
  }
}

// ---------------- flash attention: KV tile 64, DMA-staged K+V, ring-2 double buffer (64KB LDS).
// R11 lesson: 32 q-rows/wave is the right LDS-amortization point (16 halves intensity, doubles
// conflicts); occupancy is NOT binding. This round halves the per-iteration FIXED costs (barrier
// skew, vmcnt+lgkm drain, butterflies, __any, branch, loop overhead) by doubling the KV tile:
// per iteration = 64 kv, one barrier, one drain, one softmax pass per mt.
// Ring-2 depth-1: prologue STAGE(0); per iter: vmcnt(0)+lgkmcnt(0) -> barrier -> STAGE(it+1) ->
// compute(it). Race-free: lgkm drain before barrier #it guarantees slot (it+1)%2 = (it-1)%2 readers
// are serviced; STAGE(it+1) issues after the barrier. DMA lead = one full compute phase (~2x the
// R8 phase) — same absolute lead as R8's 2-phase depth.
// V rows are now 128B (8 chunks): the chunk rotation generalizes to c_store = (c - (d>>1)) & 7,
// read chunk = (h*4 + hi + (d>>1)) & 7 — keeps PV ds_read_b128 at 2-way (free) bank aliasing.
__global__ __launch_bounds__(256,2) void k_attn(
    const unsigned short* __restrict__ Qg, const unsigned short* __restrict__ Kg,
    const unsigned short* __restrict__ VT0, const unsigned short* __restrict__ VT1,
    const unsigned short* __restrict__ VT2,
    unsigned short* __restrict__ OP, float* __restrict__ LP){
  __shared__ unsigned char smem[65536];
  // K ring: 2 x 16KB at smem + s*16384 ; V ring: 2 x 16KB at smem + 32768 + s*16384

  const int tid=threadIdx.x, lane=tid&63, wid=tid>>6, ll=lane&15, hi=lane>>4;

  // ---- XCD-locality block remap: XCD x = b&7 (HW round-robin), slot i = b>>3 (0..104).
  int x = blockIdx.x & 7;
  int i = blockIdx.x >> 3;
  int sid, r;
  if (i < 60){
    r = i >> 2; int k = i & 3;
    if (k < 3){ sid = 3*x + k; }
    else { sid = 24 + (x >> 1); if (x & 1) r += 15; }
  } else {
    int t = i - 60; r = 15 + t/3; sid = 3*x + t%3;
  }
  unsigned int e = SCHED[r];
  int qb   = (int)(e & 255u);
  int t064 = (int)((e >> 8) & 255u);       // 64-row tile units (native)
  int n64  = (int)((e >> 16) & 255u);      // >= 2 for all chunks
  int slot = (int)(e >> 24);
  int br, bb, seg;
  if (sid < 16){ br=0; bb=sid>>2; seg=sid&3; }
  else if (sid < 24){ br=1; bb=(sid-16)>>1; seg=(sid-16)&1; }
  else { br=2; bb=sid-24; seg=0; }
  const int rstr = 1 << br;
  const long g0 = (long)bb*8192 + (long)seg*(2048 << br);
  const int P = sid*30 + slot;
  const unsigned short* VTb = (br==0)?VT0:(br==1)?VT1:VT2;
  const int NC = 32768 >> br;
  const int rb0 = (int)(g0 >> br);

  const int qrow_w = qb*128 + wid*32;

  bf16x8 aq[2][4];
  #pragma unroll
  for (int mt=0;mt<2;++mt){
    long gq = g0 + (long)rstr*(qrow_w + mt*16 + ll);
    const unsigned short* qp = Qg + gq*128 + hi*8;
    #pragma unroll
    for (int ks=0;ks<4;++ks) aq[mt][ks] = ld_bf8(qp + ks*32);
  }

  f32x4 o[2][8];
  #pragma unroll
  for (int mt=0;mt<2;++mt){
    #pragma unroll
    for (int dt=0;dt<8;++dt) o[mt][dt]=splat4(0.f);
  }
  float mrun[2], lrun[2];
  mrun[0]=mrun[1]=-1e30f; lrun[0]=lrun[1]=0.f;

  // ---- iteration-invariant LDS read offsets.
  // K read (nt,ks): addr = ring + nt*4096 + ll*256 + ((ks*4+hi)^(ll&7))*16   (krow&7 == ll&7)
  // V read (dt,h):  addr = ring + voff[h] + dt*2048, voff[h] = ll*128 + ((h*4+hi+(ll>>1))&7)*16
  const int m7 = ll & 7;
  int koffs[4];
  #pragma unroll
  for (int ks=0;ks<4;++ks) koffs[ks] = ll*256 + (((ks*4 + hi) ^ m7) * 16);
  const int voff0 = ll*128 + (((hi + (ll >> 1)) & 7) * 16);
  const int voff1 = ll*128 + (((4 + hi + (ll >> 1)) & 7) * 16);

  // ---- running STAGE source pointers (tiles staged strictly in order).
  // K: 4 gloads/wave: rows wid*16 + {0,4,8,12} + hi; (row&7) = {hi, 4+hi, hi, 4+hi}.
  const long kadv   = (long)rstr*64*128;
  const long kstep2 = (long)rstr*8*128;     // +8 rows
  const unsigned short* ksrc0 = Kg + (g0 + (long)rstr*((long)t064*64 + wid*16 + hi))*128 + ((ll ^ hi) * 8);
  const unsigned short* ksrc1 = Kg + (g0 + (long)rstr*((long)t064*64 + wid*16 + 4 + hi))*128 + ((ll ^ (4 + hi)) * 8);
  // V: 4 gloads/wave: li = i_*256+tid -> d = i_*32 + (tid>>3), lds chunk s = tid&7,
  // logical chunk g = (s - (d>>1))&7 = ((tid&7) - ((tid>>4)&7))&7 (i_-independent).
  const int dv = tid >> 3;
  const int gv = ((tid & 7) - ((tid >> 4) & 7)) & 7;
  const unsigned short* vsrcB = VTb + (long)dv*NC + rb0 + t064*64 + gv*8;
  const long vstep = (long)32*NC;

#define STAGE(bslot)                                                                   \
  {                                                                                    \
    unsigned char* Kb = smem + (bslot)*16384;                                          \
    unsigned char* Vb = smem + 32768 + (bslot)*16384;                                  \
    gload_lds16((const void*)ksrc0,            (void*)(Kb + wid*4096));                \
    gload_lds16((const void*)ksrc1,            (void*)(Kb + wid*4096 + 1024));         \
    gload_lds16((const void*)(ksrc0 + kstep2), (void*)(Kb + wid*4096 + 2048));         \
    gload_lds16((const void*)(ksrc1 + kstep2), (void*)(Kb + wid*4096 + 3072));         \
    gload_lds16((const void*)vsrcB,              (void*)(Vb + wid*1024));              \
    gload_lds16((const void*)(vsrcB + vstep),    (void*)(Vb + 4096 + wid*1024));       \
    gload_lds16((const void*)(vsrcB + 2*vstep),  (void*)(Vb + 8192 + wid*1024));       \
    gload_lds16((const void*)(vsrcB + 3*vstep),  (void*)(Vb + 12288 + wid*1024));      \
    ksrc0 += kadv; ksrc1 += kadv; vsrcB += 64;                                         \
  }

  // prologue: stage first tile into slot 0
  STAGE(0);

  for (int it=0; it<n64; ++it){
    const int kt = t064 + it;
    // drain ALL in-flight loads (our tile's 8) + lgkm (race-closure on slot (it-1)%2).
    asm volatile("s_waitcnt vmcnt(0) lgkmcnt(0)" ::: "memory");
    __builtin_amdgcn_s_barrier();
    __builtin_amdgcn_sched_barrier(0);

    // stage tile it+1 into the other slot: its previous readers (compute(it-1)) drained above.
    if (it + 1 < n64){
      STAGE((it + 1) & 1);
    }

    if (kt*64 <= qrow_w + 31){
      unsigned char* Kc = smem + (it & 1)*16384;
      unsigned char* Vc = smem + 32768 + (it & 1)*16384;
      // S^T = K Q^T : s[mt][nt] holds S[q=mt*16+ll][kv=kt*64+nt*16+hi*4+rr], nt=0..3
      f32x4 s[2][4];
      #pragma unroll
      for (int mt=0;mt<2;++mt){
        #pragma unroll
        for (int nt=0;nt<4;++nt) s[mt][nt]=splat4(0.f);
      }
      #pragma unroll
      for (int nt=0;nt<4;++nt){
        #pragma unroll
        for (int ks=0;ks<4;++ks){
          bf16x8 bk = ld_bf8(Kc + koffs[ks] + nt*4096);
          s[0][nt] = MFMA(bk, aq[0][ks], s[0][nt]);
          s[1][nt] = MFMA(bk, aq[1][ks], s[1][nt]);
        }
      }
      if (kt*64 + 63 > qrow_w){          // diagonal tiles: causal mask
        #pragma unroll
        for (int mt=0;mt<2;++mt){
          int qrow = qrow_w + mt*16 + ll;
          #pragma unroll
          for (int nt=0;nt<4;++nt){
            int kvcol = kt*64 + nt*16 + hi*4;
            #pragma unroll
            for (int rr=0;rr<4;++rr) if (kvcol + rr > qrow) s[mt][nt][rr] = -1e30f;
          }
        }
      }
      // online softmax (base-2), defer-max thr 8 — ONE pass per mt over 64 kv.
      bf16x8 pa[2][2];
      #pragma unroll
      for (int mt=0;mt<2;++mt){
        f32x4 t4 = vmax4(vmax4(s[mt][0], s[mt][1]), vmax4(s[mt][2], s[mt][3]));
        float mloc = fmaxf(fmaxf(t4[0],t4[1]), fmaxf(t4[2],t4[3]));
        mloc = wavemax_hi(mloc);           // VALU butterfly over hi groups
        bool upd = __any(mloc > mrun[mt] + 8.0f);
        if (upd){
          float mnew = fmaxf(mrun[mt], mloc);
          float sc = EXP2F(mrun[mt] - mnew);
          mrun[mt] = mnew;
          lrun[mt] *= sc;
          f32x4 scv;
          #pragma unroll
          for (int rr=0;rr<4;++rr) scv[rr] = __shfl(sc, hi*4 + rr, 64);
          #pragma unroll
          for (int dt=0;dt<8;++dt) o[mt][dt] = o[mt][dt]*scv;
        }
        f32x4 tsum = splat4(0.f);
        #pragma unroll
        for (int nt=0;nt<4;++nt){
          #pragma unroll
          for (int rr=0;rr<4;++rr) s[mt][nt][rr] = EXP2F(s[mt][nt][rr] - mrun[mt]);
          tsum += s[mt][nt];
        }
        lrun[mt] += (tsum[0]+tsum[1]) + (tsum[2]+tsum[3]);
        // P pack per half h: B-slot (hi,e) = kv h*32 + (e>=4)*16 + hi*4 + (e&3)
        #pragma unroll
        for (int h=0;h<2;++h){
          u16x8 up;
          #pragma unroll
          for (int rr=0;rr<4;++rr){
            up[rr]   = f2bf(s[mt][h*2][rr]);
            up[4+rr] = f2bf(s[mt][h*2+1][rr]);
          }
          pa[mt][h] = __builtin_bit_cast(bf16x8, up);
        }
      }
      // O += P V  (V^T rows d in LDS, rotated 8-chunk layout, 2-way-free b128 reads)
      #pragma unroll
      for (int dt=0;dt<8;++dt){
        bf16x8 bv0 = ld_bf8(Vc + voff0 + dt*2048);
        bf16x8 bv1 = ld_bf8(Vc + voff1 + dt*2048);
        o[0][dt] = MFMA(pa[0][0], bv0, o[0][dt]);
        o[1][dt] = MFMA(pa[1][0], bv0, o[1][dt]);
        o[0][dt] = MFMA(pa[0][1], bv1, o[0][dt]);
        o[1][dt] = MFMA(pa[1][1], bv1, o[1][dt]);
      }
    }
  }
#undef STAGE

  // epilogue: reduce lane-partial lrun across hi groups, write normalized O (bf16) + base-2 lse
  unsigned short* op = OP + (long)P*16384;
  float* lp = LP + (long)P*128;
  #pragma unroll
  for (int mt=0;mt<2;++mt){
    float l = lrun[mt];
    l += __shfl_xor(l, 16, 64);
    l += __shfl_xor(l, 32, 64);
    float invs = 1.f / l;
    f32x4 iv;
    #pragma unroll
    for (int rr=0;rr<4;++rr) iv[rr] = __shfl(invs, hi*4 + rr, 64);
    #pragma unroll
    for (int dt=0;dt<8;++dt){
      f32x4 res = o[mt][dt]*iv;
      #pragma unroll
      for (int rr=0;rr<4;++rr){
        int qloc = wid*32 + mt*16 + hi*4 + rr;
        op[qloc*128 + dt*16 + ll] = f2bf(res[rr]);
      }
    }
    float lse = mrun[mt] + LOG2F(l);
    if (lane < 16){
      lp[wid*32 + mt*16 + lane] = lse;
    }
  }
}

// ---------------- combine partials (softmax over base-2 lse) + Wo GEMM — coalesced (R8 form).
__global__ __launch_bounds__(256) void k_comb(
    const unsigned short* __restrict__ OP, const float* __restrict__ LP,
    const unsigned short* __restrict__ wT, float* __restrict__ out){
  __shared__ float Wl[9*32];                 // [s=b*3+c][row]
  __shared__ unsigned short Tl[32*136];      // combined rows bf16, row stride 136 (16B-aligned)
  const int tid = threadIdx.x;
  const long G0 = (long)blockIdx.x * 32;     // 32 rows/block, 1024 blocks = 32768 rows
  const int bb = (int)(G0 >> 13);
  const int P0 = (int)(G0 & 8191);

  // uniform per-block source decode (SALU; identical on all threads)
  int pb[3], bn[3], qlb[3];
  {
    int sid0 = bb*4 + (P0 >> 11); int qb0 = (P0 & 2047) >> 7;
    pb[0] = sid0*30 + CB[qb0]; bn[0] = (qb0<6)?1:(qb0<12)?2:3; qlb[0] = P0 & 127;
    int p1b = P0 >> 1; int sid1 = 16 + bb*2 + (p1b >> 11); int qb1 = (p1b & 2047) >> 7;
    pb[1] = sid1*30 + CB[qb1]; bn[1] = (qb1<6)?1:(qb1<12)?2:3; qlb[1] = p1b & 127;
    int p2b = P0 >> 2; int sid2 = 24 + bb; int qb2 = p2b >> 7;
    pb[2] = sid2*30 + CB[qb2]; bn[2] = (qb2<6)?1:(qb2<12)?2:3; qlb[2] = p2b & 127;
  }

  // Phase A: per-row normalized weights into Wl
  if (tid < 32){
    int i = tid;
    float Lx[9];
    #pragma unroll
    for (int b=0;b<3;++b){
      bool pv = (i & ((1<<b)-1)) == 0;
      int ql = qlb[b] + (i >> b);
      #pragma unroll
      for (int c=0;c<3;++c){
        bool v = pv && (c < bn[b]);
        Lx[b*3+c] = v ? LP[(pb[b]+c)*128 + ql] : -1e30f;
      }
    }
    float mx = -1e30f;
    #pragma unroll
    for (int s=0;s<9;++s) mx = fmaxf(mx, Lx[s]);
    float W[9]; float wsum = 0.f;
    #pragma unroll
    for (int b=0;b<3;++b){
      bool pv = (i & ((1<<b)-1)) == 0;
      #pragma unroll
      for (int c=0;c<3;++c){
        bool v = pv && (c < bn[b]);
        W[b*3+c] = v ? EXP2F(Lx[b*3+c] - mx) : 0.f;
        wsum += W[b*3+c];
      }
    }
    float inv = 1.f / wsum;
    #pragma unroll
    for (int s=0;s<9;++s) Wl[s*32 + i] = W[s] * inv;
  }
  __syncthreads();

  // Phase B: coalesced weighted combine. lane -> (row = p*16 + tid>>4, chunk = tid&15).
  {
    const int ch = tid & 15;
    const int r0 = tid >> 4;
    #pragma unroll
    for (int p=0;p<2;++p){
      int row = p*16 + r0;
      float y[8];
      #pragma unroll
      for (int j=0;j<8;++j) y[j] = 0.f;
      #pragma unroll
      for (int b=0;b<3;++b){
        if ((row & ((1<<b)-1)) == 0){
          int opr = qlb[b] + (row >> b);
          for (int c=0;c<bn[b];++c){
            float wgt = Wl[(b*3+c)*32 + row];
            const unsigned short* pp = OP + (long)(pb[b]+c)*16384 + opr*128 + ch*8;
            u16x8 u = *(const u16x8*)(const void*)pp;
            #pragma unroll
            for (int j=0;j<8;++j) y[j] += wgt * bf2f(u[j]);
          }
        }
      }
      u16x8 o;
      #pragma unroll
      for (int j=0;j<8;++j) o[j] = f2bf(y[j]);
      *(u16x8*)(void*)(Tl + row*136 + ch*8) = o;
    }
  }
  __syncthreads();

  // Phase C: Wo GEMM on the 32 combined rows — all 4 waves, 2 column-tiles each
  {
    const int wv = tid >> 6, lane = tid & 63, ll = lane & 15, hi = lane >> 4;
    bf16x8 a[2][4];
    #pragma unroll
    for (int mt=0;mt<2;++mt){
      #pragma unroll
      for (int ks=0;ks<4;++ks)
        a[mt][ks] = ld_bf8(Tl + (mt*16 + ll)*136 + ks*32 + hi*8);
    }
    const unsigned short* wp = wT + 3*16384 + ll*128 + hi*8;
    #pragma unroll
    for (int t=0;t<2;++t){
      int nt = wv*2 + t;
      f32x4 acc0=splat4(0.f), acc1=splat4(0.f);
      #pragma unroll
      for (int ks=0;ks<4;++ks){
        bf16x8 b = ld_bf8(wp + nt*2048 + ks*32);
        acc0 = MFMA(a[0][ks], b, acc0);
        acc1 = MFMA(a[1][ks], b, acc1);
      }
      #pragma unroll
      for (int rr=0;rr<4;++rr){
        out[(G0 + hi*4 + rr)*128 + nt*16 + ll]      = acc0[rr];
        out[(G0 + 16 + hi*4 + rr)*128 + nt*16 + ll] = acc1[rr];
      }
    }
  }
}

extern "C" void kernel_launch(void* const* d_in, const int* in_sizes, int n_in,
                              void* d_out, int out_size, void* d_ws, size_t ws_size,
                              hipStream_t stream){
  const float* x  = (const float*)d_in[0];
  const float* Wq = (const float*)d_in[1];
  const float* Wk = (const float*)d_in[2];
  const float* Wv = (const float*)d_in[3];
  const float* Wo = (const float*)d_in[4];
  char* ws = (char*)d_ws;
  unsigned short* wT  = (unsigned short*)(ws);                 // 131072 B
  unsigned short* Q   = (unsigned short*)(ws + 131072);        // 8388608 B
  unsigned short* K   = (unsigned short*)(ws + 8519680);       // 8388608 B
  unsigned short* VT0 = (unsigned short*)(ws + 16908288);      // 8388608 B  [128][32768] (kv-permuted)
  unsigned short* VT1 = (unsigned short*)(ws + 25296896);      // 4194304 B  [128][16384] (kv-permuted)
  unsigned short* VT2 = (unsigned short*)(ws + 29491200);      // 2097152 B  [128][8192]  (kv-permuted)
  unsigned short* OP  = (unsigned short*)(ws + 31588352);      // 27525120 B
  float* LP           = (float*)(ws + 59113472);               // 430080 B -> end 59543552
  k_prep<<<256, 256, 0, stream>>>(Wq, Wk, Wv, Wo, wT);
  k_qkv <<<256, 512, 0, stream>>>(x, wT, Q, K, VT0, VT1, VT2);
  k_attn<<<840, 256, 0, stream>>>(Q, K, VT0, VT1, VT2, OP, LP);
  k_comb<<<1024, 256, 0, stream>>>(OP, LP, wT, (float*)d_out);
}

// Round 13
// 104.217 us; speedup vs baseline: 1.0360x; 1.0360x over previous
//
#include <hip/hip_runtime.h>
#include <hip/hip_bf16.h>

typedef __attribute__((ext_vector_type(8))) __bf16 bf16x8;
typedef __attribute__((ext_vector_type(4))) float f32x4;
typedef __attribute__((ext_vector_type(8))) unsigned short u16x8;

#define DEVI __device__ __forceinline__
#define MFMA(a,b,c) __builtin_amdgcn_mfma_f32_16x16x32_bf16((a),(b),(c),0,0,0)
#define EXP2F(x) __builtin_exp2f(x)
#define LOG2F(x) __builtin_log2f(x)

DEVI unsigned short f2bf(float f){ __bf16 h = (__bf16)f; return __builtin_bit_cast(unsigned short, h); }
DEVI float bf2f(unsigned short u){ unsigned int x = ((unsigned int)u) << 16; return __builtin_bit_cast(float, x); }
DEVI bf16x8 ld_bf8(const void* p){ u16x8 u = *(const u16x8*)p; return __builtin_bit_cast(bf16x8, u); }
DEVI f32x4 splat4(float x){ f32x4 v = {x,x,x,x}; return v; }
DEVI f32x4 vmax4(f32x4 a, f32x4 b){
  f32x4 r;
  #pragma unroll
  for (int i=0;i<4;++i) r[i]=fmaxf(a[i],b[i]);
  return r;
}
DEVI void gload_lds16(const void* g, void* l){
  void* g2 = const_cast<void*>(g);
  __builtin_amdgcn_global_load_lds((__attribute__((address_space(1))) void*)g2,
                                   (__attribute__((address_space(3))) void*)l, 16, 0, 0);
}
// cross-lane max over lane-bits 4 and 5 via permlane swap butterflies (pure VALU).
#if __has_builtin(__builtin_amdgcn_permlane16_swap) && __has_builtin(__builtin_amdgcn_permlane32_swap)
DEVI float wavemax_hi(float x){
  unsigned int xu = __builtin_bit_cast(unsigned int, x);
  auto r1 = __builtin_amdgcn_permlane16_swap(xu, xu, false, false);   // xor-16 pair
  float m = fmaxf(__builtin_bit_cast(float, (unsigned int)r1[0]),
                  __builtin_bit_cast(float, (unsigned int)r1[1]));
  unsigned int mu = __builtin_bit_cast(unsigned int, m);
  auto r2 = __builtin_amdgcn_permlane32_swap(mu, mu, false, false);   // xor-32 pair
  return fmaxf(__builtin_bit_cast(float, (unsigned int)r2[0]),
               __builtin_bit_cast(float, (unsigned int)r2[1]));
}
#else
DEVI float wavemax_hi(float x){
  x = fmaxf(x, __shfl_xor(x, 16, 64));
  x = fmaxf(x, __shfl_xor(x, 32, 64));
  return x;
}
#endif

// schedule table: 30 chunks per segment, heavy-first. qb | t0<<8 | ntiles<<16 | slot<<24 (64-row tile units)
__device__ const unsigned int SCHED[30] = {
  0x100C000Bu, 0x110C0C0Bu, 0x050C0005u, 0x1C0B0A0Fu, 0x1D0B150Fu,
  0x0E0B000Au, 0x0F0B0B0Au, 0x1B0A000Fu, 0x180A000Eu, 0x190A0A0Eu,
  0x1A0A140Eu, 0x170A120Du, 0x0C0A0009u, 0x0D0A0A09u, 0x040A0004u,
  0x1509000Du, 0x1609090Du, 0x1309080Cu, 0x1409110Cu, 0x0A090008u,
  0x0B090908u, 0x1208000Cu, 0x08080007u, 0x09080807u, 0x03080003u,
  0x06070006u, 0x07070706u, 0x02060002u, 0x01040001u, 0x00020000u
};
// canonical chunk-base per qb (prefix of nchunks {1x6, 2x6, 3x4})
__device__ const int CB[16] = {0,1,2,3,4,5,6,8,10,12,14,16,18,21,24,27};

// ---------------- prep: transpose weights to [mat][col][k] bf16; fold 1/(sqrt(c)*ln2) into Wq (base-2 softmax)
__global__ __launch_bounds__(256) void k_prep(const float* __restrict__ Wq, const float* __restrict__ Wk,
                                              const float* __restrict__ Wv, const float* __restrict__ Wo,
                                              unsigned short* __restrict__ wT){
  int i = blockIdx.x*256 + threadIdx.x;              // 0..65535
  int mat = i >> 14, col = (i >> 7) & 127, k = i & 127;
  const float* W = (mat==0)?Wq:(mat==1)?Wk:(mat==2)?Wv:Wo;
  float v = W[k*128 + col];
  if (mat == 0) v *= 0.12754245006257017f;           // 1/(sqrt(128)*ln2)
  wT[i] = f2bf(v);
}

// ---------------- QKV projection + in-kernel V transpose, kv-permuted V^T arrays.
// 512-thread blocks (8 waves, 16 rows/wave) -> 2 waves/SIMD.
__global__ __launch_bounds__(512) void k_qkv(const float* __restrict__ x, const unsigned short* __restrict__ wT,
                                             unsigned short* __restrict__ Qo, unsigned short* __restrict__ Ko,
                                             unsigned short* __restrict__ VT0, unsigned short* __restrict__ VT1,
                                             unsigned short* __restrict__ VT2){
  __shared__ unsigned short Tl[128*130];             // [token 0..127][d 0..127], row stride 130
  const int tid=threadIdx.x, lane=tid&63, wid=tid>>6, ll=lane&15, hi=lane>>4;
  const int row0g = blockIdx.x*128;
  const long row0 = (long)row0g + wid*16;            // 16 rows per wave, 8 waves
  bf16x8 a[4];
  {
    const float* xr = x + (row0 + ll)*128 + hi*8;
    #pragma unroll
    for (int ks=0;ks<4;++ks){
      f32x4 f0 = *(const f32x4*)(const void*)(xr + ks*32);
      f32x4 f1 = *(const f32x4*)(const void*)(xr + ks*32 + 4);
      u16x8 u;
      #pragma unroll
      for (int j=0;j<4;++j){ u[j]=f2bf(f0[j]); u[j+4]=f2bf(f1[j]); }
      a[ks] = __builtin_bit_cast(bf16x8, u);
    }
  }
  #pragma unroll
  for (int m3=0;m3<3;++m3){
    const unsigned short* wp = wT + m3*16384 + ll*128 + hi*8;
    #pragma unroll
    for (int nt=0;nt<8;++nt){
      f32x4 acc=splat4(0.f);
      #pragma unroll
      for (int ks=0;ks<4;++ks){
        bf16x8 b = ld_bf8(wp + nt*2048 + ks*32);
        acc = MFMA(a[ks], b, acc);
      }
      if (m3 < 2){
        unsigned short* outp = (m3==0)?Qo:Ko;
        #pragma unroll
        for (int r=0;r<4;++r)
          outp[(row0 + hi*4 + r)*128 + nt*16 + ll] = f2bf(acc[r]);
      } else {
        #pragma unroll
        for (int r=0;r<4;++r)
          Tl[(wid*16 + hi*4 + r)*130 + nt*16 + ll] = f2bf(acc[r]);
      }
    }
  }
  __syncthreads();
  // write-out V^T rows, kv-permuted within 32-rank blocks (rank pair 2*lane,2*lane+1 stays adjacent)
  int tk = 2*lane;
  int pp0 = (tk>>5)*32 + ((tk>>4)&1)*4 + ((tk&15)>>2)*8 + (tk&3);
  #pragma unroll 4
  for (int p=0;p<16;++p){
    int d = wid*16 + p;
    unsigned int w0 = (unsigned int)Tl[(2*lane)*130 + d] | ((unsigned int)Tl[(2*lane+1)*130 + d] << 16);
    *(unsigned int*)(VT0 + (long)d*32768 + row0g + pp0) = w0;
    if (lane < 32){
      unsigned int w1 = (unsigned int)Tl[(4*lane)*130 + d] | ((unsigned int)Tl[(4*lane+2)*130 + d] << 16);
      *(unsigned int*)(VT1 + (long)d*16384 + (row0g>>1) + pp0) = w1;
    }
    if (lane < 16){
      unsigned int w2 = (unsigned int)Tl[(8*lane)*130 + d] | ((unsigned int)Tl[(8*lane+4)*130 + d] << 16);
      *(unsigned int*)(VT2 + (long)d*8192 + (row0g>>2) + pp0) = w2;
    }
  }
}

// ---------------- flash attention: KV tile 32, DMA-staged K+V, ring-3 buffers (R8 best: 56.2us).
// Session ledger: R9 speculative-exp (-4.4us), R10 comb-merge (-1.4), R11 16-row/wave (-3.0,
// conflicts x2), R12 KV-64 ring-2 (-4.3, occupancy 15%, conflicts x2, vmcnt(0) exposed DMA) —
// all reverted. This 32-rows/wave, KV-32, ring-3, counted-vmcnt balance is the measured optimum
// in every direction probed; K and V LDS patterns are at the theoretical 8-accesses/bank minimum.
// Per iteration: counted vmcnt + lgkm drain -> s_barrier -> STAGE(it+2) -> compute(it).
// Race-free: lgkmcnt(0) before the barrier guarantees slot-((it-1)%3) LDS reads are SERVICED before
// the wave signals barrier #it; STAGE(it+2) (overwriting that slot) issues only after the barrier.
__global__ __launch_bounds__(256,3) void k_attn(
    const unsigned short* __restrict__ Qg, const unsigned short* __restrict__ Kg,
    const unsigned short* __restrict__ VT0, const unsigned short* __restrict__ VT1,
    const unsigned short* __restrict__ VT2,
    unsigned short* __restrict__ OP, float* __restrict__ LP){
  __shared__ unsigned char smem[49152];
  // K ring: 3 x 8KB at smem + s*8192 ; V ring: 3 x 8KB at smem + 24576 + s*8192

  const int tid=threadIdx.x, lane=tid&63, wid=tid>>6, ll=lane&15, hi=lane>>4;

  // ---- XCD-locality block remap: XCD x = b&7 (HW round-robin), slot i = b>>3 (0..104).
  int x = blockIdx.x & 7;
  int i = blockIdx.x >> 3;
  int sid, r;
  if (i < 60){
    r = i >> 2; int k = i & 3;
    if (k < 3){ sid = 3*x + k; }
    else { sid = 24 + (x >> 1); if (x & 1) r += 15; }
  } else {
    int t = i - 60; r = 15 + t/3; sid = 3*x + t%3;
  }
  unsigned int e = SCHED[r];
  int qb   = (int)(e & 255u);
  int t032 = (int)((e >> 8) & 255u) * 2;
  int n32  = (int)((e >> 16) & 255u) * 2;
  int slot = (int)(e >> 24);
  int br, bb, seg;
  if (sid < 16){ br=0; bb=sid>>2; seg=sid&3; }
  else if (sid < 24){ br=1; bb=(sid-16)>>1; seg=(sid-16)&1; }
  else { br=2; bb=sid-24; seg=0; }
  const int rstr = 1 << br;
  const long g0 = (long)bb*8192 + (long)seg*(2048 << br);
  const int P = sid*30 + slot;
  const unsigned short* VTb = (br==0)?VT0:(br==1)?VT1:VT2;
  const int NC = 32768 >> br;
  const int rb0 = (int)(g0 >> br);

  const int qrow_w = qb*128 + wid*32;

  bf16x8 aq[2][4];
  #pragma unroll
  for (int mt=0;mt<2;++mt){
    long gq = g0 + (long)rstr*(qrow_w + mt*16 + ll);
    const unsigned short* qp = Qg + gq*128 + hi*8;
    #pragma unroll
    for (int ks=0;ks<4;++ks) aq[mt][ks] = ld_bf8(qp + ks*32);
  }

  f32x4 o[2][8];
  #pragma unroll
  for (int mt=0;mt<2;++mt){
    #pragma unroll
    for (int dt=0;dt<8;++dt) o[mt][dt]=splat4(0.f);
  }
  float mrun[2], lrun[2];
  mrun[0]=mrun[1]=-1e30f; lrun[0]=lrun[1]=0.f;

  // ---- iteration-invariant LDS read offsets.
  const int m7 = ll & 7;
  int koffs[4];
  #pragma unroll
  for (int ks=0;ks<4;++ks) koffs[ks] = ll*256 + (((ks*4 + hi) ^ m7) * 16);
  const int voffb = ll*64 + (((hi + (ll >> 1)) & 3) * 16);

  // ---- running STAGE source pointers (tiles staged strictly in order t032, t032+1, ...).
  const long kadv = (long)rstr*32*128;
  const unsigned short* ksrc0 = Kg + (g0 + (long)rstr*((long)t032*32 + wid*8 + hi))*128 + ((ll ^ hi) * 8);
  const unsigned short* ksrc1 = Kg + (g0 + (long)rstr*((long)t032*32 + wid*8 + 4 + hi))*128 + ((ll ^ (4 + hi)) * 8);
  const int d0_ = tid >> 2,        s0_ = tid & 3,        ga_ = (s0_ - (d0_ >> 1)) & 3;
  const int d1_ = (256+tid) >> 2,  s1_ = tid & 3,        gb_ = (s1_ - (d1_ >> 1)) & 3;
  const unsigned short* vsrc0 = VTb + (long)d0_*NC + rb0 + t032*32 + ga_*8;
  const unsigned short* vsrc1 = VTb + (long)d1_*NC + rb0 + t032*32 + gb_*8;

  // stage next tile into ring slot bslot: 2 K-gloads + 2 V-gloads per wave; advance pointers
#define STAGE(bslot)                                                                   \
  {                                                                                    \
    unsigned char* Kb = smem + (bslot)*8192;                                           \
    unsigned char* Vb = smem + 24576 + (bslot)*8192;                                   \
    gload_lds16((const void*)ksrc0, (void*)(Kb + wid*2048));                           \
    gload_lds16((const void*)ksrc1, (void*)(Kb + wid*2048 + 1024));                    \
    gload_lds16((const void*)vsrc0, (void*)(Vb + wid*1024));                           \
    gload_lds16((const void*)vsrc1, (void*)(Vb + 4096 + wid*1024));                    \
    ksrc0 += kadv; ksrc1 += kadv; vsrc0 += 32; vsrc1 += 32;                            \
  }

  // prologue: stage first two tiles into slots 0,1 (n32 >= 2 always)
  STAGE(0);
  STAGE(1);

  for (int it=0; it<n32; ++it){
    const int kt = t032 + it;
    // drain OWN batch before the barrier; lgkmcnt(0) closes the ds_read-vs-DMA race on slot (it-1)%3.
    if (it + 1 < n32){
      asm volatile("s_waitcnt vmcnt(4) lgkmcnt(0)" ::: "memory");
    } else {
      asm volatile("s_waitcnt vmcnt(0) lgkmcnt(0)" ::: "memory");
    }
    __builtin_amdgcn_s_barrier();
    __builtin_amdgcn_sched_barrier(0);

    // stage tile it+2 right after the barrier: slot (it+2)%3 = (it-1)%3 is free.
    if (it + 2 < n32){
      STAGE((it + 2) % 3);
    }

    if (kt*32 <= qrow_w + 31){
      unsigned char* Kc = smem + (it % 3)*8192;
      unsigned char* Vc = smem + 24576 + (it % 3)*8192;
      // S^T = K Q^T : s[mt][nt] holds S[q=mt*16+ll][kv=kt*32+nt*16+hi*4+rr]
      f32x4 s[2][2];
      #pragma unroll
      for (int mt=0;mt<2;++mt){
        #pragma unroll
        for (int nt=0;nt<2;++nt) s[mt][nt]=splat4(0.f);
      }
      #pragma unroll
      for (int nt=0;nt<2;++nt){
        #pragma unroll
        for (int ks=0;ks<4;++ks){
          bf16x8 bk = ld_bf8(Kc + koffs[ks] + nt*4096);
          s[0][nt] = MFMA(bk, aq[0][ks], s[0][nt]);
          s[1][nt] = MFMA(bk, aq[1][ks], s[1][nt]);
        }
      }
      if (kt*32 + 31 > qrow_w){          // diagonal tiles: causal mask
        #pragma unroll
        for (int mt=0;mt<2;++mt){
          int qrow = qrow_w + mt*16 + ll;
          #pragma unroll
          for (int nt=0;nt<2;++nt){
            int kvcol = kt*32 + nt*16 + hi*4;
            #pragma unroll
            for (int rr=0;rr<4;++rr) if (kvcol + rr > qrow) s[mt][nt][rr] = -1e30f;
          }
        }
      }
      // online softmax (base-2), defer-max thr 8; lane ll owns q = mt*16+ll.
      // lrun kept lane-partial (reduced in epilogue).
      #pragma unroll
      for (int mt=0;mt<2;++mt){
        f32x4 t4 = vmax4(s[mt][0], s[mt][1]);
        float mloc = fmaxf(fmaxf(t4[0],t4[1]), fmaxf(t4[2],t4[3]));
        mloc = wavemax_hi(mloc);           // VALU butterfly over hi groups
        bool upd = __any(mloc > mrun[mt] + 8.0f);
        if (upd){
          float mnew = fmaxf(mrun[mt], mloc);
          float sc = EXP2F(mrun[mt] - mnew);
          mrun[mt] = mnew;
          lrun[mt] *= sc;
          f32x4 scv;
          #pragma unroll
          for (int rr=0;rr<4;++rr) scv[rr] = __shfl(sc, hi*4 + rr, 64);
          #pragma unroll
          for (int dt=0;dt<8;++dt) o[mt][dt] = o[mt][dt]*scv;
        }
        f32x4 tsum = splat4(0.f);
        #pragma unroll
        for (int nt=0;nt<2;++nt){
          #pragma unroll
          for (int rr=0;rr<4;++rr) s[mt][nt][rr] = EXP2F(s[mt][nt][rr] - mrun[mt]);
          tsum += s[mt][nt];
        }
        lrun[mt] += (tsum[0]+tsum[1]) + (tsum[2]+tsum[3]);
      }
      // P pack: LANE-LOCAL (kv-permuted V^T makes B-slot (hi,e) = kv (e>=4)*16+hi*4+(e&3))
      bf16x8 pa[2];
      #pragma unroll
      for (int mt=0;mt<2;++mt){
        u16x8 up;
        #pragma unroll
        for (int rr=0;rr<4;++rr){
          up[rr]   = f2bf(s[mt][0][rr]);
          up[4+rr] = f2bf(s[mt][1][rr]);
        }
        pa[mt] = __builtin_bit_cast(bf16x8, up);
      }
      // O += P V  (V^T rows d in LDS, conflict-free swizzled b128 reads, base+imm addressing)
      #pragma unroll
      for (int dt=0;dt<8;++dt){
        bf16x8 bv = ld_bf8(Vc + voffb + dt*1024);
        o[0][dt] = MFMA(pa[0], bv, o[0][dt]);
        o[1][dt] = MFMA(pa[1], bv, o[1][dt]);
      }
    }
  }
#undef STAGE

  // epilogue: reduce lane-partial lrun across hi groups, write normalized O (bf16) + base-2 lse
  unsigned short* op = OP + (long)P*16384;
  float* lp = LP + (long)P*128;
  #pragma unroll
  for (int mt=0;mt<2;++mt){
    float l = lrun[mt];
    l += __shfl_xor(l, 16, 64);
    l += __shfl_xor(l, 32, 64);
    float invs = 1.f / l;
    f32x4 iv;
    #pragma unroll
    for (int rr=0;rr<4;++rr) iv[rr] = __shfl(invs, hi*4 + rr, 64);
    #pragma unroll
    for (int dt=0;dt<8;++dt){
      f32x4 res = o[mt][dt]*iv;
      #pragma unroll
      for (int rr=0;rr<4;++rr){
        int qloc = wid*32 + mt*16 + hi*4 + rr;
        op[qloc*128 + dt*16 + ll] = f2bf(res[rr]);
      }
    }
    float lse = mrun[mt] + LOG2F(l);
    if (lane < 16){
      lp[wid*32 + mt*16 + lane] = lse;
    }
  }
}

// ---------------- combine partials (softmax over base-2 lse) + Wo GEMM — coalesced (R8 form).
// 32 output rows per block, grid 1024. Phase A: 32 threads compute per-row normalized weights
// into LDS. Phase B: 256 threads, coalesced weighted sum (16 lanes x 16B per row), rows staged
// in LDS bf16. Phase C: all 4 waves run the Wo GEMM, 2 column-tiles each.
__global__ __launch_bounds__(256) void k_comb(
    const unsigned short* __restrict__ OP, const float* __restrict__ LP,
    const unsigned short* __restrict__ wT, float* __restrict__ out){
  __shared__ float Wl[9*32];                 // [s=b*3+c][row]
  __shared__ unsigned short Tl[32*136];      // combined rows bf16, row stride 136 (16B-aligned)
  const int tid = threadIdx.x;
  const long G0 = (long)blockIdx.x * 32;     // 32 rows/block, 1024 blocks = 32768 rows
  const int bb = (int)(G0 >> 13);
  const int P0 = (int)(G0 & 8191);

  // uniform per-block source decode (SALU; identical on all threads)
  int pb[3], bn[3], qlb[3];
  {
    int sid0 = bb*4 + (P0 >> 11); int qb0 = (P0 & 2047) >> 7;
    pb[0] = sid0*30 + CB[qb0]; bn[0] = (qb0<6)?1:(qb0<12)?2:3; qlb[0] = P0 & 127;
    int p1b = P0 >> 1; int sid1 = 16 + bb*2 + (p1b >> 11); int qb1 = (p1b & 2047) >> 7;
    pb[1] = sid1*30 + CB[qb1]; bn[1] = (qb1<6)?1:(qb1<12)?2:3; qlb[1] = p1b & 127;
    int p2b = P0 >> 2; int sid2 = 24 + bb; int qb2 = p2b >> 7;
    pb[2] = sid2*30 + CB[qb2]; bn[2] = (qb2<6)?1:(qb2<12)?2:3; qlb[2] = p2b & 127;
  }

  // Phase A: per-row normalized weights into Wl
  if (tid < 32){
    int i = tid;
    float Lx[9];
    #pragma unroll
    for (int b=0;b<3;++b){
      bool pv = (i & ((1<<b)-1)) == 0;
      int ql = qlb[b] + (i >> b);
      #pragma unroll
      for (int c=0;c<3;++c){
        bool v = pv && (c < bn[b]);
        Lx[b*3+c] = v ? LP[(pb[b]+c)*128 + ql] : -1e30f;
      }
    }
    float mx = -1e30f;
    #pragma unroll
    for (int s=0;s<9;++s) mx = fmaxf(mx, Lx[s]);
    float W[9]; float wsum = 0.f;
    #pragma unroll
    for (int b=0;b<3;++b){
      bool pv = (i & ((1<<b)-1)) == 0;
      #pragma unroll
      for (int c=0;c<3;++c){
        bool v = pv && (c < bn[b]);
        W[b*3+c] = v ? EXP2F(Lx[b*3+c] - mx) : 0.f;
        wsum += W[b*3+c];
      }
    }
    float inv = 1.f / wsum;
    #pragma unroll
    for (int s=0;s<9;++s) Wl[s*32 + i] = W[s] * inv;
  }
  __syncthreads();

  // Phase B: coalesced weighted combine. lane -> (row = p*16 + tid>>4, chunk = tid&15).
  {
    const int ch = tid & 15;
    const int r0 = tid >> 4;
    #pragma unroll
    for (int p=0;p<2;++p){
      int row = p*16 + r0;
      float y[8];
      #pragma unroll
      for (int j=0;j<8;++j) y[j] = 0.f;
      #pragma unroll
      for (int b=0;b<3;++b){
        if ((row & ((1<<b)-1)) == 0){
          int opr = qlb[b] + (row >> b);
          for (int c=0;c<bn[b];++c){
            float wgt = Wl[(b*3+c)*32 + row];
            const unsigned short* pp = OP + (long)(pb[b]+c)*16384 + opr*128 + ch*8;
            u16x8 u = *(const u16x8*)(const void*)pp;
            #pragma unroll
            for (int j=0;j<8;++j) y[j] += wgt * bf2f(u[j]);
          }
        }
      }
      u16x8 o;
      #pragma unroll
      for (int j=0;j<8;++j) o[j] = f2bf(y[j]);
      *(u16x8*)(void*)(Tl + row*136 + ch*8) = o;
    }
  }
  __syncthreads();

  // Phase C: Wo GEMM on the 32 combined rows — all 4 waves, 2 column-tiles each
  {
    const int wv = tid >> 6, lane = tid & 63, ll = lane & 15, hi = lane >> 4;
    bf16x8 a[2][4];
    #pragma unroll
    for (int mt=0;mt<2;++mt){
      #pragma unroll
      for (int ks=0;ks<4;++ks)
        a[mt][ks] = ld_bf8(Tl + (mt*16 + ll)*136 + ks*32 + hi*8);
    }
    const unsigned short* wp = wT + 3*16384 + ll*128 + hi*8;
    #pragma unroll
    for (int t=0;t<2;++t){
      int nt = wv*2 + t;
      f32x4 acc0=splat4(0.f), acc1=splat4(0.f);
      #pragma unroll
      for (int ks=0;ks<4;++ks){
        bf16x8 b = ld_bf8(wp + nt*2048 + ks*32);
        acc0 = MFMA(a[0][ks], b, acc0);
        acc1 = MFMA(a[1][ks], b, acc1);
      }
      #pragma unroll
      for (int rr=0;rr<4;++rr){
        out[(G0 + hi*4 + rr)*128 + nt*16 + ll]      = acc0[rr];
        out[(G0 + 16 + hi*4 + rr)*128 + nt*16 + ll] = acc1[rr];
      }
    }
  }
}

extern "C" void kernel_launch(void* const* d_in, const int* in_sizes, int n_in,
                              void* d_out, int out_size, void* d_ws, size_t ws_size,
                              hipStream_t stream){
  const float* x  = (const float*)d_in[0];
  const float* Wq = (const float*)d_in[1];
  const float* Wk = (const float*)d_in[2];
  const float* Wv = (const float*)d_in[3];
  const float* Wo = (const float*)d_in[4];
  char* ws = (char*)d_ws;
  unsigned short* wT  = (unsigned short*)(ws);                 // 131072 B
  unsigned short* Q   = (unsigned short*)(ws + 131072);        // 8388608 B
  unsigned short* K   = (unsigned short*)(ws + 8519680);       // 8388608 B
  unsigned short* VT0 = (unsigned short*)(ws + 16908288);      // 8388608 B  [128][32768] (kv-permuted)
  unsigned short* VT1 = (unsigned short*)(ws + 25296896);      // 4194304 B  [128][16384] (kv-permuted)
  unsigned short* VT2 = (unsigned short*)(ws + 29491200);      // 2097152 B  [128][8192]  (kv-permuted)
  unsigned short* OP  = (unsigned short*)(ws + 31588352);      // 27525120 B
  float* LP           = (float*)(ws + 59113472);               // 430080 B -> end 59543552
  k_prep<<<256, 256, 0, stream>>>(Wq, Wk, Wv, Wo, wT);
  k_qkv <<<256, 512, 0, stream>>>(x, wT, Q, K, VT0, VT1, VT2);
  k_attn<<<840, 256, 0, stream>>>(Q, K, VT0, VT1, VT2, OP, LP);
  k_comb<<<1024, 256, 0, stream>>>(OP, LP, wT, (float*)d_out);
}